// Round 2
// 661.943 us; speedup vs baseline: 1.2724x; 1.2724x over previous
//
#include <hip/hip_runtime.h>
#include <math.h>

#define DDIM 16
#define NSTEPS 64

typedef __fp16   fp16x2  __attribute__((ext_vector_type(2)));
typedef _Float16 half4   __attribute__((ext_vector_type(4)));
typedef float    floatx4 __attribute__((ext_vector_type(4)));

// Bit-cast two packed-f16 pairs (from v_cvt_pkrtz_f16_f32) into one half4
// MFMA operand without element-wise conversion instructions.
union pk2_to_h4 {
    fp16x2 p2[2];
    half4  h4;
};

// ---------------------------------------------------------------------------
// Pre-pack W^T / V^T into per-lane MFMA A-operand fragments (f16).
// For v_mfma_f32_16x16x16_f16, A[m][k]: lane L supplies m = L&15, k = 4*(L>>4)+j.
// We feed A = W_s^T, so lane L, elem j holds W_s^T[L&15][4q+j] = W_s[4q+j][L&15].
// V fragments are pre-scaled by 1/NSTEPS so the main loop never multiplies by it.
// ---------------------------------------------------------------------------
__global__ __launch_bounds__(256) void pack_wv(const float* __restrict__ W,
                                               const float* __restrict__ V,
                                               half4* __restrict__ pw,
                                               half4* __restrict__ pv)
{
    int t = blockIdx.x * 256 + threadIdx.x;   // 0..4095 = 64 steps * 64 lanes
    int L = t & 63;
    int s = t >> 6;
    int q = L >> 4, r = L & 15;
    const float inv_n = 1.0f / (float)NSTEPS;
    const float* Ws = W + s * DDIM * DDIM;
    const float* Vs = V + s * DDIM * DDIM;
    half4 w, v;
    #pragma unroll
    for (int j = 0; j < 4; ++j) {
        w[j] = (_Float16)Ws[(4 * q + j) * DDIM + r];
        v[j] = (_Float16)(Vs[(4 * q + j) * DDIM + r] * inv_n);
    }
    pw[t] = w;
    pv[t] = v;
}

// ---------------------------------------------------------------------------
// Main kernel: each wave owns 4 row-tiles (64 rows). State h kept in fp32 in
// the MFMA C/D layout: lane L holds h[row = L&15][cols 4q..4q+3] of its tile.
// Chain (all transposed):  u^T = W^T @ h^T ;  h^T += (V^T/N) @ gelu(u)^T.
// C/D layout == B-operand layout for the transposed chain -> no shuffles/LDS.
// VALU-lean inner loop: pkrtz packed f16 conversions, 5 full-rate + 2 trans
// ops per element for GELU, 1/N folded into V fragments.
// ---------------------------------------------------------------------------
__global__ __launch_bounds__(256) void resnet_mfma_kernel(
    const float* __restrict__ x,
    const half4* __restrict__ pw,
    const half4* __restrict__ pv,
    float* __restrict__ out)
{
    const int tid  = threadIdx.x;
    const int lane = tid & 63;
    const int wave = tid >> 6;
    const int q = lane >> 4, r = lane & 15;

    const long rowbase = (long)blockIdx.x * 256 + (long)wave * 64;

    // Load state: lane reads float4 at (row, 4q) for each of its 4 tiles.
    floatx4 h[4];
    #pragma unroll
    for (int t = 0; t < 4; ++t) {
        const float4* p = reinterpret_cast<const float4*>(
            x + (rowbase + t * 16 + r) * DDIM + 4 * q);
        float4 v = *p;
        h[t][0] = v.x; h[t][1] = v.y; h[t][2] = v.z; h[t][3] = v.w;
    }

    const float K0  = 2.3022082f;    // 0.7978845608 * 2 * log2(e)
    const float KC1 = 0.10294324f;   // K0 * 0.044715

    // Software-prefetch the W/V fragments one step ahead (L1/L2-hot, 64KB total).
    half4 wf = pw[lane];
    half4 vf = pv[lane];

    for (int s = 0; s < NSTEPS; ++s) {
        int sn = (s + 1) & (NSTEPS - 1);          // last iter wraps to 0 (unused)
        half4 wfn = pw[sn * 64 + lane];
        half4 vfn = pv[sn * 64 + lane];

        #pragma unroll
        for (int t = 0; t < 4; ++t) {
            // h (fp32, C/D layout) -> f16 B-operand via packed RTZ converts
            pk2_to_h4 hc;
            hc.p2[0] = __builtin_amdgcn_cvt_pkrtz(h[t][0], h[t][1]);
            hc.p2[1] = __builtin_amdgcn_cvt_pkrtz(h[t][2], h[t][3]);

            floatx4 zero = {0.f, 0.f, 0.f, 0.f};
            floatx4 u = __builtin_amdgcn_mfma_f32_16x16x16f16(wf, hc.h4, zero, 0, 0, 0);

            // g = GELU(u) (tanh form), 5 full-rate + 2 trans ops per element.
            // 1/N is already folded into vf.
            float g0[4];
            #pragma unroll
            for (int j = 0; j < 4; ++j) {
                float xv = u[j];
                float s2 = xv * xv;
                float a  = fmaf(KC1, s2, K0);      // K*(1 + c1*x^2)
                float z  = xv * a;                 // K*(x + c1*x^3)
                float e  = __builtin_amdgcn_exp2f(z);
                float rr = __builtin_amdgcn_rcpf(1.0f + e);
                g0[j] = fmaf(-xv, rr, xv);         // x * (1 - 1/(1+2^z)) = x*sigmoid
            }
            pk2_to_h4 gc;
            gc.p2[0] = __builtin_amdgcn_cvt_pkrtz(g0[0], g0[1]);
            gc.p2[1] = __builtin_amdgcn_cvt_pkrtz(g0[2], g0[3]);

            // h += gelu(u) @ (V/N)  (residual add folded into MFMA C operand)
            h[t] = __builtin_amdgcn_mfma_f32_16x16x16f16(vf, gc.h4, h[t], 0, 0, 0);
        }

        wf = wfn; vf = vfn;
    }

    #pragma unroll
    for (int t = 0; t < 4; ++t) {
        float4 v = make_float4(h[t][0], h[t][1], h[t][2], h[t][3]);
        *reinterpret_cast<float4*>(out + (rowbase + t * 16 + r) * DDIM + 4 * q) = v;
    }
}

extern "C" void kernel_launch(void* const* d_in, const int* in_sizes, int n_in,
                              void* d_out, int out_size, void* d_ws, size_t ws_size,
                              hipStream_t stream) {
    const float* x = (const float*)d_in[0];   // [B, 16] fp32
    const float* W = (const float*)d_in[1];   // [64, 16, 16] fp32
    const float* V = (const float*)d_in[2];   // [64, 16, 16] fp32
    float* out = (float*)d_out;

    half4* pw = (half4*)d_ws;                 // 64 steps * 64 lanes * 8B = 32KB
    half4* pv = pw + NSTEPS * 64;             // +32KB (ws_size must be >= 64KB)

    pack_wv<<<16, 256, 0, stream>>>(W, V, pw, pv);

    int batch = in_sizes[0] / DDIM;           // 2^21
    resnet_mfma_kernel<<<batch / 256, 256, 0, stream>>>(x, pw, pv, out);
}

// Round 3
// 475.569 us; speedup vs baseline: 1.7711x; 1.3919x over previous
//
#include <hip/hip_runtime.h>
#include <math.h>

#define DDIM 16
#define NSTEPS 64
#define LUT_N 1024          // segments over [-8, 8]
#define LUT_SCALE 64.0f     // LUT_N / 16
#define LUT_BIAS 512.0f     // 8 * LUT_SCALE

typedef __fp16   fp16x2  __attribute__((ext_vector_type(2)));
typedef _Float16 half4   __attribute__((ext_vector_type(4)));
typedef float    floatx4 __attribute__((ext_vector_type(4)));

union pk2_to_h4 {
    fp16x2 p2[2];
    half4  h4;
};

// ---------------------------------------------------------------------------
// Pre-pack W^T / V^T into per-lane MFMA A-operand fragments (f16).
// V fragments are pre-scaled by 1/NSTEPS.
// ---------------------------------------------------------------------------
__global__ __launch_bounds__(256) void pack_wv(const float* __restrict__ W,
                                               const float* __restrict__ V,
                                               half4* __restrict__ pw,
                                               half4* __restrict__ pv)
{
    int t = blockIdx.x * 256 + threadIdx.x;   // 0..4095 = 64 steps * 64 lanes
    int L = t & 63;
    int s = t >> 6;
    int q = L >> 4, r = L & 15;
    const float inv_n = 1.0f / (float)NSTEPS;
    const float* Ws = W + s * DDIM * DDIM;
    const float* Vs = V + s * DDIM * DDIM;
    half4 w, v;
    #pragma unroll
    for (int j = 0; j < 4; ++j) {
        w[j] = (_Float16)Ws[(4 * q + j) * DDIM + r];
        v[j] = (_Float16)(Vs[(4 * q + j) * DDIM + r] * inv_n);
    }
    pw[t] = w;
    pv[t] = v;
}

// ---------------------------------------------------------------------------
// Build a piecewise-linear LUT for EXACT (erf) GELU over [-8, 8].
// Entry i: (a, b) with gelu(x) ~= a*x + b on segment i.
// Clamped-index extrapolation is exact: last segment a~=1,b~=0 -> g=x for x>8;
// first segment a~=0,b~=0 -> g=0 for x<-8.
// ---------------------------------------------------------------------------
__global__ __launch_bounds__(256) void build_lut(float2* __restrict__ lut)
{
    int i = blockIdx.x * 256 + threadIdx.x;   // 0..1023
    const float h = 16.0f / (float)LUT_N;
    float x0 = -8.0f + i * h;
    float x1 = x0 + h;
    float g0 = 0.5f * x0 * (1.0f + erff(x0 * 0.70710678f));
    float g1 = 0.5f * x1 * (1.0f + erff(x1 * 0.70710678f));
    float a = (g1 - g0) * LUT_SCALE;
    float b = g0 - a * x0;
    lut[i] = make_float2(a, b);
}

// ---------------------------------------------------------------------------
// Main kernel: each wave owns 4 row-tiles (64 rows). State h kept in fp32 in
// the MFMA C/D layout. Chain (all transposed):
//   u^T = W^T @ h^T ;  h^T += (V^T/N) @ gelu(u)^T.
// GELU via LDS LUT gather: 5 VALU + 1 ds_read_b64 per element -> no
// transcendental ops in the loop (they were the ~60% floor at R1).
// ---------------------------------------------------------------------------
__global__ __launch_bounds__(256) void resnet_mfma_kernel(
    const float* __restrict__ x,
    const half4* __restrict__ pw,
    const half4* __restrict__ pv,
    const float2* __restrict__ lut_g,
    float* __restrict__ out)
{
    __shared__ float2 lut[LUT_N];   // 8 KB

    const int tid  = threadIdx.x;
    const int lane = tid & 63;
    const int wave = tid >> 6;
    const int q = lane >> 4, r = lane & 15;

    // Stage LUT into LDS: 512 float4 (= 1024 float2) / 256 threads = 2 each.
    {
        const float4* src = reinterpret_cast<const float4*>(lut_g);
        float4* dst = reinterpret_cast<float4*>(lut);
        dst[tid]       = src[tid];
        dst[tid + 256] = src[tid + 256];
    }

    const long rowbase = (long)blockIdx.x * 256 + (long)wave * 64;

    // Load state: lane reads float4 at (row, 4q) for each of its 4 tiles.
    floatx4 h[4];
    #pragma unroll
    for (int t = 0; t < 4; ++t) {
        const float4* p = reinterpret_cast<const float4*>(
            x + (rowbase + t * 16 + r) * DDIM + 4 * q);
        float4 v = *p;
        h[t][0] = v.x; h[t][1] = v.y; h[t][2] = v.z; h[t][3] = v.w;
    }

    // Software-prefetch the W/V fragments one step ahead (L1/L2-hot, 64KB total).
    half4 wf = pw[lane];
    half4 vf = pv[lane];

    __syncthreads();   // LUT ready

    for (int s = 0; s < NSTEPS; ++s) {
        int sn = (s + 1) & (NSTEPS - 1);          // last iter wraps to 0 (unused)
        half4 wfn = pw[sn * 64 + lane];
        half4 vfn = pv[sn * 64 + lane];

        #pragma unroll
        for (int t = 0; t < 4; ++t) {
            // h (fp32, C/D layout) -> f16 B-operand via packed RTZ converts
            pk2_to_h4 hc;
            hc.p2[0] = __builtin_amdgcn_cvt_pkrtz(h[t][0], h[t][1]);
            hc.p2[1] = __builtin_amdgcn_cvt_pkrtz(h[t][2], h[t][3]);

            floatx4 zero = {0.f, 0.f, 0.f, 0.f};
            floatx4 u = __builtin_amdgcn_mfma_f32_16x16x16f16(wf, hc.h4, zero, 0, 0, 0);

            // g = GELU(u) via LDS LUT (1/N folded into vf).
            float g0[4];
            #pragma unroll
            for (int j = 0; j < 4; ++j) {
                float xv = u[j];
                float tf = fmaf(xv, LUT_SCALE, LUT_BIAS);
                float tc = __builtin_amdgcn_fmed3f(tf, 0.0f, (float)(LUT_N - 1));
                unsigned idx = (unsigned)tc;
                float2 ab = lut[idx];
                g0[j] = fmaf(ab.x, xv, ab.y);
            }
            pk2_to_h4 gc;
            gc.p2[0] = __builtin_amdgcn_cvt_pkrtz(g0[0], g0[1]);
            gc.p2[1] = __builtin_amdgcn_cvt_pkrtz(g0[2], g0[3]);

            // h += gelu(u) @ (V/N)  (residual add folded into MFMA C operand)
            h[t] = __builtin_amdgcn_mfma_f32_16x16x16f16(vf, gc.h4, h[t], 0, 0, 0);
        }

        wf = wfn; vf = vfn;
    }

    #pragma unroll
    for (int t = 0; t < 4; ++t) {
        float4 v = make_float4(h[t][0], h[t][1], h[t][2], h[t][3]);
        *reinterpret_cast<float4*>(out + (rowbase + t * 16 + r) * DDIM + 4 * q) = v;
    }
}

extern "C" void kernel_launch(void* const* d_in, const int* in_sizes, int n_in,
                              void* d_out, int out_size, void* d_ws, size_t ws_size,
                              hipStream_t stream) {
    const float* x = (const float*)d_in[0];   // [B, 16] fp32
    const float* W = (const float*)d_in[1];   // [64, 16, 16] fp32
    const float* V = (const float*)d_in[2];   // [64, 16, 16] fp32
    float* out = (float*)d_out;

    half4* pw = (half4*)d_ws;                 // 64 steps * 64 lanes * 8B = 32KB
    half4* pv = pw + NSTEPS * 64;             // +32KB
    float2* lut = (float2*)(pv + NSTEPS * 64);// +8KB  (ws_size must be >= 72KB)

    pack_wv<<<16, 256, 0, stream>>>(W, V, pw, pv);
    build_lut<<<LUT_N / 256, 256, 0, stream>>>(lut);

    int batch = in_sizes[0] / DDIM;           // 2^21
    resnet_mfma_kernel<<<batch / 256, 256, 0, stream>>>(x, pw, pv, lut, out);
}